// Round 13
// baseline (191.752 us; speedup 1.0000x reference)
//
#include <hip/hip_runtime.h>
#include <hip/hip_bf16.h>
#include <stdint.h>

#define BATCH 2
#define LQ 2048
#define LK 2048
#define DIM 1024
#define HEADS 8
#define DH 64
#define INNER 512  // HEADS*DH

typedef __attribute__((ext_vector_type(8))) short short8;
typedef __attribute__((ext_vector_type(4))) float f32x4;
typedef __attribute__((ext_vector_type(16))) float f32x16;

__device__ __forceinline__ float bf2f(unsigned short u) {
    union { unsigned int i; float f; } v;
    v.i = ((unsigned int)u) << 16;
    return v.f;
}
__device__ __forceinline__ unsigned short f2bf(float f) {
    __hip_bfloat16 h = __float2bfloat16(f);
    return *reinterpret_cast<unsigned short*>(&h);
}
// raw v_exp_f32 (2^x); __expf would add a *log2e mul we fold into QSCALE
__device__ __forceinline__ float fexp2(float x) {
#if __has_builtin(__builtin_amdgcn_exp2f)
    return __builtin_amdgcn_exp2f(x);
#else
    return __expf(x * 0.69314718056f);
#endif
}
__device__ __forceinline__ void stc(unsigned short* C, size_t i, float v) { C[i] = f2bf(v); }
__device__ __forceinline__ void stc(float* C, size_t i, float v) { C[i] = v; }

// packed f32x2 -> bf16x2 (RNE), single instruction (T12 recipe; no builtin)
__device__ __forceinline__ unsigned cvtpk_bf16(float lo, float hi) {
    unsigned r;
    asm("v_cvt_pk_bf16_f32 %0, %1, %2" : "=v"(r) : "v"(lo), "v"(hi));
    return r;
}
// permlane32_swap: x' = [x_lo32 | y_lo32], y' = [x_hi32 | y_hi32]
__device__ __forceinline__ void perm32swap(unsigned& a, unsigned& b) {
#if __has_builtin(__builtin_amdgcn_permlane32_swap)
    auto r = __builtin_amdgcn_permlane32_swap(a, b, false, false);
    a = r[0]; b = r[1];
#else
    asm volatile("v_permlane32_swap_b32 %0, %1" : "+v"(a), "+v"(b));
#endif
}

// Direct global->LDS DMA, 16B/lane. LDS dest = wave-uniform base + lane*16.
typedef __attribute__((address_space(1))) const unsigned int gu32;
typedef __attribute__((address_space(3))) unsigned int lu32;
__device__ __forceinline__ void gload16(const void* g, void* l) {
    __builtin_amdgcn_global_load_lds((gu32*)g, (lu32*)l, 16, 0, 0);
}

// ---------------------------------------------------------------------------
// prep: fp32->bf16 copies (y=0..5, scalar RNE cvt) + mask bit-pack (y=6),
// one launch. (unchanged this round)
// ---------------------------------------------------------------------------
__global__ __launch_bounds__(256) void prep(
    const float* __restrict__ x,  const float* __restrict__ y,
    const float* __restrict__ wq, const float* __restrict__ wk,
    const float* __restrict__ wv, const float* __restrict__ wo,
    const float* __restrict__ mask,
    unsigned short* __restrict__ xb,  unsigned short* __restrict__ yb,
    unsigned short* __restrict__ wqb, unsigned short* __restrict__ wkb,
    unsigned short* __restrict__ wvb, unsigned short* __restrict__ wob,
    unsigned long long* __restrict__ mbits)
{
    if (blockIdx.y == 6) {
        const int wid = blockIdx.x * 4 + (threadIdx.x >> 6);   // 4096 waves
        const int lane = threadIdx.x & 63;
        for (int task = wid; task < BATCH * LQ * 8; task += 4096) {
            int row = task >> 3, g = task & 7;
            const float* mp = mask + (size_t)row * LK + g * 256;
            unsigned long long* ob = mbits + (size_t)row * (LK / 64) + g * 4;
            float v0 = mp[0 * 64 + lane];
            float v1 = mp[1 * 64 + lane];
            float v2 = mp[2 * 64 + lane];
            float v3 = mp[3 * 64 + lane];
            unsigned long long b0 = __ballot(v0 > 0.5f);
            unsigned long long b1 = __ballot(v1 > 0.5f);
            unsigned long long b2 = __ballot(v2 > 0.5f);
            unsigned long long b3 = __ballot(v3 > 0.5f);
            if (lane == 0) { ob[0] = b0; ob[1] = b1; ob[2] = b2; ob[3] = b3; }
        }
        return;
    }
    const float* src; unsigned short* dst; int n4;
    switch (blockIdx.y) {
        case 0: src = x;  dst = xb;  n4 = (BATCH * LQ * DIM) / 4; break;
        case 1: src = y;  dst = yb;  n4 = (BATCH * LK * DIM) / 4; break;
        case 2: src = wq; dst = wqb; n4 = (INNER * DIM) / 4; break;
        case 3: src = wk; dst = wkb; n4 = (INNER * DIM) / 4; break;
        case 4: src = wv; dst = wvb; n4 = (INNER * DIM) / 4; break;
        default: src = wo; dst = wob; n4 = (INNER * DIM) / 4; break;
    }
    const int stride = gridDim.x * 256;
    for (int i = blockIdx.x * 256 + threadIdx.x; i < n4; i += stride) {
        float4 f = ((const float4*)src)[i];
        ushort4 u;
        u.x = f2bf(f.x); u.y = f2bf(f.y); u.z = f2bf(f.z); u.w = f2bf(f.w);
        ((ushort4*)dst)[i] = u;
    }
}

// ---------------------------------------------------------------------------
// C = scale * (A[M,K] @ W[N,K]^T), bf16 in, fp32 accum.
// 128x128 tile, 8 waves (2x4), BK=64, swizzled global_load_lds staging,
// double-buffered, one barrier/K-tile. (unchanged this round)
// ---------------------------------------------------------------------------
template <int IM, int JN, int WR, int WC, typename TC, int EPI>
__device__ __forceinline__ void gemm_body(
    const unsigned short* __restrict__ A,
    const unsigned short* __restrict__ W,
    TC* __restrict__ C,
    int K, int N, float scale,
    unsigned short* SH)
{
    constexpr int THREADS = WR * WC * 64;
    constexpr int BM = WR * IM * 16;
    constexpr int BN = WC * JN * 16;
    constexpr int ACH = BM * 8;     // 16B chunks per A tile
    constexpr int BCH = BN * 8;
    constexpr int AUS = BM * 64;    // shorts per A buffer
    constexpr int BUS = BN * 64;

    unsigned short* As = SH;
    unsigned short* Bs = SH + 2 * AUS;

    const int tid = threadIdx.x;
    const int m0 = blockIdx.x * BM;
    const int n0 = blockIdx.y * BN;
    const int w = tid >> 6, lane = tid & 63;
    const int q4 = lane >> 4, l16 = lane & 15;
    const int wm = (w / WC) * (IM * 16), wn = (w % WC) * (JN * 16);
    const int sw = l16 & 7;

    f32x4 acc[IM][JN] = {};

#pragma unroll
    for (int i = 0; i < ACH / THREADS; ++i) {
        int s = tid + i * THREADS;
        int r = s >> 3, ch = (s & 7) ^ (r & 7);
        gload16(A + (size_t)(m0 + r) * K + ch * 8, As + (size_t)s * 8);
    }
#pragma unroll
    for (int i = 0; i < BCH / THREADS; ++i) {
        int s = tid + i * THREADS;
        int r = s >> 3, ch = (s & 7) ^ (r & 7);
        gload16(W + (size_t)(n0 + r) * K + ch * 8, Bs + (size_t)s * 8);
    }
    __syncthreads();

    const int nt = K / 64;
    for (int t = 0; t < nt; ++t) {
        const int curA = (t & 1) * AUS;
        const int curB = (t & 1) * BUS;
        if (t + 1 < nt) {
            int kk = (t + 1) * 64;
            const int nxtA = AUS - curA, nxtB = BUS - curB;
#pragma unroll
            for (int i = 0; i < ACH / THREADS; ++i) {
                int s = tid + i * THREADS;
                int r = s >> 3, ch = (s & 7) ^ (r & 7);
                gload16(A + (size_t)(m0 + r) * K + kk + ch * 8, As + nxtA + (size_t)s * 8);
            }
#pragma unroll
            for (int i = 0; i < BCH / THREADS; ++i) {
                int s = tid + i * THREADS;
                int r = s >> 3, ch = (s & 7) ^ (r & 7);
                gload16(W + (size_t)(n0 + r) * K + kk + ch * 8, Bs + nxtB + (size_t)s * 8);
            }
        }

#pragma unroll
        for (int ks = 0; ks < 2; ++ks) {
            const int kq = ((ks * 4 + q4) ^ sw) * 8;
            short8 a[IM], b[JN];
#pragma unroll
            for (int i = 0; i < IM; ++i)
                a[i] = *(const short8*)(As + curA + (wm + i * 16 + l16) * 64 + kq);
#pragma unroll
            for (int j = 0; j < JN; ++j)
                b[j] = *(const short8*)(Bs + curB + (wn + j * 16 + l16) * 64 + kq);
#pragma unroll
            for (int i = 0; i < IM; ++i)
#pragma unroll
                for (int j = 0; j < JN; ++j)
                    acc[i][j] = __builtin_amdgcn_mfma_f32_16x16x32_bf16(
                        a[i], b[j], acc[i][j], 0, 0, 0);
        }
        __syncthreads();
    }

    if (EPI == 0) {
        // C/D layout: col = lane&15, row = quad*4 + reg  [m89-verified]
#pragma unroll
        for (int i = 0; i < IM; ++i)
#pragma unroll
            for (int j = 0; j < JN; ++j)
#pragma unroll
                for (int r = 0; r < 4; ++r) {
                    int row = m0 + wm + i * 16 + q4 * 4 + r;
                    int col = n0 + wn + j * 16 + l16;
                    stc(C, (size_t)row * N + col, acc[i][j][r] * scale);
                }
    } else {
        // V-transpose epilogue into vt[((b*H+h)*DH+d)*LK + key].
        constexpr int KW = IM * 16;
        constexpr int DW = JN * 16;
        constexpr int TPS = KW + 8;
        unsigned short* TP = SH + w * (DW * TPS);
#pragma unroll
        for (int i = 0; i < IM; ++i)
#pragma unroll
            for (int j = 0; j < JN; ++j) {
                ushort4 u;
                u.x = f2bf(acc[i][j][0]); u.y = f2bf(acc[i][j][1]);
                u.z = f2bf(acc[i][j][2]); u.w = f2bf(acc[i][j][3]);
                *(ushort4*)(TP + (j * 16 + l16) * TPS + i * 16 + q4 * 4) = u;
            }
        const int keyflat = m0 + wm;
        const int bb = keyflat >> 11, key0 = keyflat & (LK - 1);
        const int hh = (n0 + wn) >> 6;
        const int dlow = (n0 + wn) & 63;
        constexpr int RCH = KW / 8;
        constexpr int NCH = DW * RCH;
#pragma unroll
        for (int p = 0; p < NCH / 64; ++p) {
            int c = p * 64 + lane;
            int dl = c / RCH, kc = c % RCH;
            uint4 v = *(const uint4*)(TP + dl * TPS + kc * 8);
            *(uint4*)((unsigned short*)C +
                ((size_t)((bb * HEADS + hh) * DH + dlow + dl)) * LK + key0 + kc * 8) = v;
        }
    }
}

// q scaled by 0.125*log2(e) so attn uses raw v_exp_f32 (2^x) directly.
#define QSCALE 0.18033688011112042f

__global__ __launch_bounds__(512) void proj_qkv(
    const unsigned short* __restrict__ xb, const unsigned short* __restrict__ yb,
    const unsigned short* __restrict__ wqb, const unsigned short* __restrict__ wkb,
    const unsigned short* __restrict__ wvb,
    unsigned short* __restrict__ qb, unsigned short* __restrict__ kb,
    unsigned short* __restrict__ vt)
{
    __shared__ __align__(16) unsigned short SH[4 * 128 * 64];  // 64 KB
    const int z = blockIdx.z;
    const unsigned short* A = (z == 0) ? xb : yb;
    const unsigned short* W = (z == 0) ? wqb : (z == 1) ? wkb : wvb;
    if (z == 2)
        gemm_body<4, 2, 2, 4, unsigned short, 1>(A, W, vt, DIM, INNER, 1.0f, SH);
    else
        gemm_body<4, 2, 2, 4, unsigned short, 0>(A, W, (z == 0) ? qb : kb, DIM, INNER,
                                                 (z == 0) ? QSCALE : 1.0f, SH);
}

__global__ __launch_bounds__(512) void gemm_out(
    const unsigned short* __restrict__ A,
    const unsigned short* __restrict__ W,
    float* __restrict__ C)
{
    __shared__ __align__(16) unsigned short SH[4 * 128 * 64];  // 64 KB
    gemm_body<4, 2, 2, 4, float, 0>(A, W, C, INNER, DIM, 1.0f, SH);
}

// ---------------------------------------------------------------------------
// Flash attention v8: de-phasing via 4 independent blocks/CU.
// Diagnosis: v5/v6/v7 falsified per-pipe models; no pipe saturated, grid
// was 512 = exactly 2 blocks/CU and all 16 waves lockstep on one barrier ->
// phases (staging BW, LDS read, MFMA, softmax VALU, drain) serialize.
// Fix: 32 q-rows/block, 4 waves (kh x par), 256 thr, grid 1024 = 4
// blocks/CU, each at a different round -> phases interleave across blocks.
// LDS fits 4 blocks by staging K ONLY (4-slot ring, 32 KB); V fragments
// are read straight from global/L2 into registers at round top (QK+softmax
// ~600 cyc covers L2 latency -- the cover v4 lacked). 32x32 MFMA math,
// T12 softmax, mask nibbles, T1 h=bid&7, T5 setprio all unchanged from v7
// (qh removed: q = l31 spans the block's 32 rows).
// ---------------------------------------------------------------------------
#define KSLOT (64 * 64)   // shorts per K tile slot (8 KB)

__global__ __launch_bounds__(256, 4) void attn_mfma(
    const unsigned short* __restrict__ Q,
    const unsigned short* __restrict__ Kb,
    const unsigned short* __restrict__ Vt,
    const unsigned long long* __restrict__ Mb,
    unsigned short* __restrict__ O)
{
    __shared__ __align__(16) unsigned short Ks[4 * KSLOT];   // 32 KB

    const int tid = threadIdx.x;
    const int L = blockIdx.x;                 // 1024 blocks
    const int h = L & 7;                      // T1: head == XCD slot
    const int jj = L >> 3;                    // 0..127
    const int b = jj >> 6;                    // batch
    const int q0 = (jj & 63) * 32;            // 32-row q-block
    const int w = tid >> 6, lane = tid & 63;
    const int kh = w & 1;                     // 32-key half
    const int par = w >> 1;                   // tile parity
    const int l31 = lane & 31, hl = lane >> 5;
    const int l7 = lane & 7;

    // Q as B-operand frags (32x32x16): col q = l31, k-window = ks*16+8*hl
    short8 qf[4];
    {
        const unsigned short* qp =
            Q + (size_t)(b * LQ + q0 + l31) * INNER + h * DH + 8 * hl;
#pragma unroll
        for (int ks = 0; ks < 4; ++ks)
            qf[ks] = *(const short8*)(qp + ks * 16);
    }

    f32x16 o[2] = {};
    float lacc = 0.f;

    const unsigned short* kbase = Kb + (size_t)(b * LK) * INNER + h * DH;
    const unsigned short* vbase = Vt + (size_t)((b * HEADS + h) * DH) * LK;
    const unsigned long long* mrow =
        Mb + (size_t)(b * LQ + q0 + l31) * (LK / 64);

    // K staging: 256 threads stage one 64x64 tile in two row-halves
    const int r0 = tid >> 3, ch0 = (tid & 7) ^ (r0 & 7);
    const int s1 = tid + 256;
    const int r1 = s1 >> 3, ch1 = (s1 & 7) ^ (r1 & 7);

    // prologue: K tiles 0,1 -> slots 0,1
#pragma unroll
    for (int tn = 0; tn < 2; ++tn) {
        gload16(kbase + (size_t)(tn * 64 + r0) * INNER + ch0 * 8,
                Ks + tn * KSLOT + (size_t)tid * 8);
        gload16(kbase + (size_t)(tn * 64 + r1) * INNER + ch1 * 8,
                Ks + tn * KSLOT + (size_t)s1 * 8);
    }
    __syncthreads();

    const int NR = LK / 128;   // 16 rounds, 2 tiles each
    for (int rd = 0; rd < NR; ++rd) {
        if (rd + 1 < NR) {
#pragma unroll
            for (int i = 0; i < 2; ++i) {
                const int tn = 2 * rd + 2 + i;
                const int sl = tn & 3;
                gload16(kbase + (size_t)(tn * 64 + r0) * INNER + ch0 * 8,
                        Ks + sl * KSLOT + (size_t)tid * 8);
                gload16(kbase + (size_t)(tn * 64 + r1) * INNER + ch1 * 8,
                        Ks + sl * KSLOT + (size_t)s1 * 8);
            }
        }
        const int t = 2 * rd + par;
        const int cur = (t & 3) * KSLOT;

        // ---- V frags for this round: straight from global/L2 into regs.
        // Issued before QK so the QK+softmax phase covers the L2 latency.
        short8 vf[2][2];
#pragma unroll
        for (int df = 0; df < 2; ++df)
#pragma unroll
            for (int k2 = 0; k2 < 2; ++k2)
                vf[df][k2] = *(const short8*)(vbase
                    + (size_t)(df * 32 + l31) * LK + t * 64
                    + (kh * 4 + k2 * 2 + hl) * 8);

        // ---- S^T = K Q^T : one 32x32 acc over 4 ksteps ----
        f32x16 s = {};
        __builtin_amdgcn_s_setprio(1);
#pragma unroll
        for (int ks = 0; ks < 4; ++ks) {
            const int R = kh * 32 + l31;             // key row in tile
            const int c0 = ks * 2 + hl;              // 8-elem k-chunk
            short8 kf = *(const short8*)(Ks + cur + R * 64 + ((c0 ^ l7) * 8));
            s = __builtin_amdgcn_mfma_f32_32x32x16_bf16(kf, qf[ks], s, 0, 0, 0);
        }
        __builtin_amdgcn_s_setprio(0);

        // ---- p = masked ? 0 : 2^s ; cvtpk pairs ----
        unsigned bits32 = (unsigned)(mrow[t] >> (kh * 32));
        unsigned pk[8];
#pragma unroll
        for (int g = 0; g < 4; ++g) {
            unsigned nib = (bits32 >> (8 * g + 4 * hl)) & 0xFu;
            float p0 = (nib & 1u) ? 0.f : fexp2(s[4 * g + 0]);
            float p1 = (nib & 2u) ? 0.f : fexp2(s[4 * g + 1]);
            float p2 = (nib & 4u) ? 0.f : fexp2(s[4 * g + 2]);
            float p3 = (nib & 8u) ? 0.f : fexp2(s[4 * g + 3]);
            lacc += (p0 + p1) + (p2 + p3);
            pk[2 * g]     = cvtpk_bf16(p0, p1);
            pk[2 * g + 1] = cvtpk_bf16(p2, p3);
        }

        // ---- P^T B-frags via permlane32 (no LDS) ----
        short8 pf[2];
#pragma unroll
        for (int k2 = 0; k2 < 2; ++k2) {
            unsigned r0u = pk[4 * k2 + 0], r2u = pk[4 * k2 + 2];
            unsigned r1u = pk[4 * k2 + 1], r3u = pk[4 * k2 + 3];
            perm32swap(r0u, r2u);   // -> reg0, reg2
            perm32swap(r1u, r3u);   // -> reg1, reg3
            union { unsigned u[4]; short8 s8; } up;
            up.u[0] = r0u; up.u[1] = r1u; up.u[2] = r2u; up.u[3] = r3u;
            pf[k2] = up.s8;
        }

        // ---- O^T += V^T P^T over this wave's 32 keys (vf from regs) ----
        __builtin_amdgcn_s_setprio(1);
#pragma unroll
        for (int df = 0; df < 2; ++df)
#pragma unroll
            for (int k2 = 0; k2 < 2; ++k2)
                o[df] = __builtin_amdgcn_mfma_f32_32x32x16_bf16(
                    vf[df][k2], pf[k2], o[df], 0, 0, 0);
        __builtin_amdgcn_s_setprio(0);
        __syncthreads();
    }

    // ---- 4-way partial combine (kh x par) through dead K LDS ----
    // stride 33 floats (odd) => conflict-free. 3*64*33*4 = 25344 B <= 32 KB.
    float* xch = (float*)Ks;
    const int wslot = par * 2 + kh;          // 0 = leader
    if (wslot) {
        float* d = xch + (size_t)((wslot - 1) * 64 + lane) * 33;
#pragma unroll
        for (int df = 0; df < 2; ++df)
#pragma unroll
            for (int r = 0; r < 16; ++r) d[df * 16 + r] = o[df][r];
        d[32] = lacc;
    }
    __syncthreads();
    if (!wslot) {
#pragma unroll
        for (int ws2 = 0; ws2 < 3; ++ws2) {
            const float* d = xch + (size_t)(ws2 * 64 + lane) * 33;
#pragma unroll
            for (int df = 0; df < 2; ++df)
#pragma unroll
                for (int r = 0; r < 16; ++r) o[df][r] += d[df * 16 + r];
            lacc += d[32];
        }
        // hl halves hold disjoint key sets for the same q
        lacc += __shfl_xor(lacc, 32);
        const float inv = 1.0f / lacc;

        // store: q = l31 row; d = df*32 + 8g + 4hl + (0..3)
        unsigned short* orow =
            O + (size_t)(b * LQ + q0 + l31) * INNER + h * DH;
#pragma unroll
        for (int df = 0; df < 2; ++df)
#pragma unroll
            for (int g = 0; g < 4; ++g) {
                ushort4 u;
                u.x = f2bf(o[df][4 * g + 0] * inv);
                u.y = f2bf(o[df][4 * g + 1] * inv);
                u.z = f2bf(o[df][4 * g + 2] * inv);
                u.w = f2bf(o[df][4 * g + 3] * inv);
                *(ushort4*)(orow + df * 32 + 8 * g + 4 * hl) = u;
            }
    }
}

extern "C" void kernel_launch(void* const* d_in, const int* in_sizes, int n_in,
                              void* d_out, int out_size, void* d_ws, size_t ws_size,
                              hipStream_t stream) {
    const float* x    = (const float*)d_in[0];
    const float* y    = (const float*)d_in[1];
    const float* mask = (const float*)d_in[2];
    const float* Wq   = (const float*)d_in[3];
    const float* Wk   = (const float*)d_in[4];
    const float* Wv   = (const float*)d_in[5];
    const float* Wo   = (const float*)d_in[6];
    float* out = (float*)d_out;

    const size_t NX = (size_t)BATCH * LQ * DIM;    // 4.19M
    const size_t NS = (size_t)BATCH * LQ * INNER;  // 2.10M
    const size_t NW = (size_t)INNER * DIM;         // 0.52M
    unsigned short* xb  = (unsigned short*)d_ws;
    unsigned short* yb  = xb + NX;
    unsigned short* qb  = yb + NX;
    unsigned short* kb  = qb + NS;
    unsigned short* vt  = kb + NS;
    unsigned short* wqb = vt + NS;
    unsigned short* wkb = wqb + NW;
    unsigned short* wvb = wkb + NW;
    unsigned short* wob = wvb + NW;
    unsigned long long* mbits = (unsigned long long*)(wob + NW);
    unsigned short* ao  = xb;   // xb dead after proj
    // ws: 33.8 MB bf16 + 1 MB bits

    dim3 blk(256);
    prep<<<dim3(1024, 7), blk, 0, stream>>>(
        x, y, Wq, Wk, Wv, Wo, mask, xb, yb, wqb, wkb, wvb, wob, mbits);
    proj_qkv<<<dim3(4096 / 128, INNER / 128, 3), dim3(512), 0, stream>>>(
        xb, yb, wqb, wkb, wvb, qb, kb, vt);
    attn_mfma<<<dim3(1024), dim3(256), 0, stream>>>(
        qb, kb, vt, mbits, ao);
    gemm_out<<<dim3(4096 / 128, DIM / 128), dim3(512), 0, stream>>>(ao, wob, out);
}